// Round 5
// baseline (134.637 us; speedup 1.0000x reference)
//
#include <hip/hip_runtime.h>
#include <hip/hip_bf16.h>
#include <math.h>

// Problem constants
#define NB    4096
#define DH    784
#define KX    800            // 784 padded; 12 BK-64 stages + 32-col tail
#define NSR   5
#define NNEG  (NB*NSR)       // 20480
#define NTOT  (NB + NNEG)    // 24576

#define A_CONST 1.576943f
#define PEXP    1.7901216f   // 2*B_PARAM
#define EPS_C   1.0e-4f
#define ALPHA_C 0.9296875f   // BATCH_COUNT=500: beta=0.5*(1-500/800)^2=0.0703125
#define BETA_C  0.0703125f

#define NSLOT 64             // per row: 32 block-contribs x 2 wave-halves
#define SLAB  (NB * NSLOT)   // elements per stat component = 262144
#define NBLK  528            // upper-triangular 32x32 block grid (8*66)
#define BUFE  8192           // LDS buffer stride in bf16 elems (128*64)

typedef __hip_bfloat16 bf16;
typedef short bf16x8 __attribute__((ext_vector_type(8)));
typedef float f32x4  __attribute__((ext_vector_type(4)));

// Workspace layout (bytes)
#define WS_XBF    0                      // 4096*800*2 = 6553600
#define WS_EBF    6553600                // 4096*32*2  = 262144
#define WS_SQX    6815744                // 4096*4     = 16384
#define WS_SQE    6832128                // 4096*4     = 16384
#define WS_STATSP 6848512                // 5*262144*4 = 5242880
#define WS_UPART  12091392               // 96*4       = 384
#define WS_CPART  12091776               // 64*4       = 256
#define WS_CNT    12092032               // 4

__device__ __forceinline__ void gl2lds16(const bf16* g, bf16* l) {
    __builtin_amdgcn_global_load_lds(
        (const __attribute__((address_space(1))) unsigned int*)g,
        (__attribute__((address_space(3))) unsigned int*)l,
        16, 0, 0);
}

// ---- fused prep: blocks 0..1023 -> X cast+pad+sqnorm; 1024..1119 -> UMAP CE + e_to prep
__global__ void prep_fused(const float* __restrict__ X, const float* __restrict__ emb,
                           const int* __restrict__ perm, bf16* __restrict__ Xbf,
                           float* __restrict__ sqx, bf16* __restrict__ Ebf,
                           float* __restrict__ sqe, float* __restrict__ upart,
                           unsigned* __restrict__ cnt) {
    if (blockIdx.x == 0 && threadIdx.x == 0) *cnt = 0u;   // for finish1 last-block
    if (blockIdx.x < 1024) {
        // prep X: 4 waves/block, one row per wave, float4 loads. 196 float4/row.
        const int wave = threadIdx.x >> 6, lane = threadIdx.x & 63;
        const int row = blockIdx.x * 4 + wave;
        const float4* xr = (const float4*)(X + (size_t)row * DH);
        bf16* xb = Xbf + (size_t)row * KX;
        float s = 0.f;
        #pragma unroll
        for (int it = 0; it < 4; ++it) {
            const int idx = lane + it * 64;
            if (idx < 196) {
                float4 v = xr[idx];
                s += v.x * v.x + v.y * v.y + v.z * v.z + v.w * v.w;
                union { bf16 h[4]; ushort4 u; } cv;
                cv.h[0] = __float2bfloat16(v.x);
                cv.h[1] = __float2bfloat16(v.y);
                cv.h[2] = __float2bfloat16(v.z);
                cv.h[3] = __float2bfloat16(v.w);
                *(ushort4*)(xb + idx * 4) = cv.u;
            }
        }
        if (lane < 16) xb[DH + lane] = __float2bfloat16(0.f);   // pad 784..799
        #pragma unroll
        for (int off = 32; off; off >>= 1) s += __shfl_down(s, off, 64);
        if (lane == 0) sqx[row] = s;
        return;
    }
    // UMAP CE + e_to bf16 prep
    const int ub = blockIdx.x - 1024;
    const int t = ub * 256 + threadIdx.x;
    float val = 0.f;
    if (t < NB) {
        const float4* av = (const float4*)(emb + (size_t)t * 32);
        float4 t0 = av[0], t1 = av[1], t2 = av[2], t3 = av[3];   // e_to
        float4 f0 = av[4], f1 = av[5], f2 = av[6], f3 = av[7];   // e_from
        bf16* eb = Ebf + (size_t)t * 32;
        union { bf16 h[4]; ushort4 u; } cv;
        #define ST4(dst, q) cv.h[0]=__float2bfloat16(q.x); cv.h[1]=__float2bfloat16(q.y); \
                            cv.h[2]=__float2bfloat16(q.z); cv.h[3]=__float2bfloat16(q.w); \
                            *(ushort4*)(dst) = cv.u;
        ST4(eb,      t0) ST4(eb + 4,  t1) ST4(eb + 8,  t2) ST4(eb + 12, t3)
        #undef ST4
        ushort4 z = {0, 0, 0, 0};
        *(ushort4*)(eb + 16) = z; *(ushort4*)(eb + 20) = z;
        *(ushort4*)(eb + 24) = z; *(ushort4*)(eb + 28) = z;
        sqe[t] = t0.x*t0.x + t0.y*t0.y + t0.z*t0.z + t0.w*t0.w
               + t1.x*t1.x + t1.y*t1.y + t1.z*t1.z + t1.w*t1.w
               + t2.x*t2.x + t2.y*t2.y + t2.z*t2.z + t2.w*t2.w
               + t3.x*t3.x + t3.y*t3.y + t3.z*t3.z + t3.w*t3.w;
        float d2 = 0.f;
        #define D2(a, b) { float4 df = {a.x-b.x, a.y-b.y, a.z-b.z, a.w-b.w}; \
                           d2 += df.x*df.x + df.y*df.y + df.z*df.z + df.w*df.w; }
        D2(t0, f0) D2(t1, f1) D2(t2, f2) D2(t3, f3)
        #undef D2
        float d = sqrtf(d2);
        float p = 1.f / (1.f + A_CONST * powf(d, PEXP));
        val = -logf(fminf(fmaxf(p, EPS_C), 1.f));
    } else if (t < NTOT) {
        const int k = t - NB;
        const int ti = k / 5;
        const int fi = perm[k] / 5;
        const float4* at = (const float4*)(emb + (size_t)ti * 32);
        const float4* bt = (const float4*)(emb + (size_t)fi * 32 + 16);
        float d2 = 0.f;
        #pragma unroll
        for (int q = 0; q < 4; ++q) {
            float4 a = at[q], b = bt[q];
            float4 df = {a.x-b.x, a.y-b.y, a.z-b.z, a.w-b.w};
            d2 += df.x*df.x + df.y*df.y + df.z*df.z + df.w*df.w;
        }
        float d = sqrtf(d2);
        float p = 1.f / (1.f + A_CONST * powf(d, PEXP));
        val = -logf(fminf(fmaxf(1.f - p, EPS_C), 1.f));
    }
    #pragma unroll
    for (int off = 32; off; off >>= 1) val += __shfl_down(val, off, 64);
    __shared__ float ps[4];
    if ((threadIdx.x & 63) == 0) ps[threadIdx.x >> 6] = val;
    __syncthreads();
    if (threadIdx.x == 0) upart[ub] = ps[0] + ps[1] + ps[2] + ps[3];
}

// ---- main: upper-triangular 128x128 dual-gram, BK=64 double-buffered,
// K-staggered start (decorrelate panel reads across blocks), XOR-swizzled
// LDS (conflict-free b128), streamed E-gram epilogue, symmetric stats.
__global__ __launch_bounds__(256, 2) void gram_kernel(
    const bf16* __restrict__ Xbf, const bf16* __restrict__ Ebf,
    const float* __restrict__ sqx, const float* __restrict__ sqe,
    float* __restrict__ statsp) {
    __shared__ bf16 As[2 * BUFE];   // 32 KB (double-buffered 128x64)
    __shared__ bf16 Bs[2 * BUFE];   // 32 KB
    __shared__ float sqxs[256];     // [0..127]=i rows, [128..255]=j cols
    __shared__ float sqes[256];

    // XCD swizzle: 528 = 8*66; XCD k gets 66 consecutive triangle entries.
    int n = (blockIdx.x & 7) * 66 + (blockIdx.x >> 3);
    int bi = 0;
    while (n >= 32 - bi) { n -= 32 - bi; ++bi; }
    const int bj = bi + n;
    const int i0 = bi * 128, j0 = bj * 128;
    const int off = (bi * 5 + bj) % 12;   // K-stagger

    const int tid  = threadIdx.x;
    const int wave = tid >> 6;
    const int lane = tid & 63;
    const int wy = wave >> 1, wx = wave & 1;
    const int quad = lane >> 4, l15 = lane & 15;

    f32x4 acc[4][4];
    #pragma unroll
    for (int a = 0; a < 4; ++a)
        #pragma unroll
        for (int b = 0; b < 4; ++b)
            acc[a][b] = (f32x4){0.f, 0.f, 0.f, 0.f};

    // staging: 16 groups of 8 rows; wave stages groups {4w..4w+3}.
    // lane L: row-in-group L>>3, logical 16B seg sl=(L&7)^((L>>3)&7) (swizzle:
    // LDS[row][p] holds global seg p^(row&7)).
    const int g0   = wave * 4;
    const int lrow = lane >> 3;
    const int sl   = (lane & 7) ^ (lrow & 7);

    const bf16* pA[4]; const bf16* pB[4]; const bf16* tA[4]; const bf16* tB[4];
    #pragma unroll
    for (int g = 0; g < 4; ++g) {
        const int rA = i0 + (g0 + g) * 8 + lrow;
        const int rB = j0 + (g0 + g) * 8 + lrow;
        pA[g] = Xbf + (size_t)rA * KX + sl * 8;
        pB[g] = Xbf + (size_t)rB * KX + sl * 8;
        // tail stage: segs 0..3 = X cols 768..799; segs 4..7 = E (128x32)
        tA[g] = (sl < 4) ? Xbf + (size_t)rA * KX + 768 + sl * 8
                         : Ebf + (size_t)rA * 32 + (sl - 4) * 8;
        tB[g] = (sl < 4) ? Xbf + (size_t)rB * KX + 768 + sl * 8
                         : Ebf + (size_t)rB * 32 + (sl - 4) * 8;
    }

    // prologue: prefetch stage off into buf 0
    #pragma unroll
    for (int g = 0; g < 4; ++g) {
        gl2lds16(pA[g] + off * 64, As + (g0 + g) * 512);
        gl2lds16(pB[g] + off * 64, Bs + (g0 + g) * 512);
    }

    if (tid < 128) {
        sqxs[tid] = sqx[i0 + tid]; sqxs[128 + tid] = sqx[j0 + tid];
        sqes[tid] = sqe[i0 + tid]; sqes[128 + tid] = sqe[j0 + tid];
    }

    // fragment positions (swizzled): h=0 -> quad^(l15&7), h=1 -> (4+quad)^(l15&7)
    const int l7   = l15 & 7;
    const int pos0 = (quad ^ l7) * 8;
    const int pos1 = ((4 + quad) ^ l7) * 8;

    for (int t = 0; t < 12; ++t) {
        __syncthreads();                       // drains prefetch of buf[t&1]
        const int cur = (t & 1) * BUFE;
        const int nb  = ((t + 1) & 1) * BUFE;
        if (t < 11) {                          // prefetch next full stage
            const int s = (t + 1 + off) % 12;
            #pragma unroll
            for (int g = 0; g < 4; ++g) {
                gl2lds16(pA[g] + s * 64, As + nb + (g0 + g) * 512);
                gl2lds16(pB[g] + s * 64, Bs + nb + (g0 + g) * 512);
            }
        } else {                               // prefetch tail(X 32) + E into buf 0
            #pragma unroll
            for (int g = 0; g < 4; ++g) {
                gl2lds16(tA[g], As + nb + (g0 + g) * 512);
                gl2lds16(tB[g], Bs + nb + (g0 + g) * 512);
            }
        }
        bf16x8 af0[4], af1[4], bf0[4], bf1[4];
        #pragma unroll
        for (int mi = 0; mi < 4; ++mi) {
            const int r = (wy * 64 + mi * 16 + l15) * 64;
            af0[mi] = *(const bf16x8*)&As[cur + r + pos0];
            af1[mi] = *(const bf16x8*)&As[cur + r + pos1];
        }
        #pragma unroll
        for (int ni = 0; ni < 4; ++ni) {
            const int r = (wx * 64 + ni * 16 + l15) * 64;
            bf0[ni] = *(const bf16x8*)&Bs[cur + r + pos0];
            bf1[ni] = *(const bf16x8*)&Bs[cur + r + pos1];
        }
        #pragma unroll
        for (int mi = 0; mi < 4; ++mi)
            #pragma unroll
            for (int ni = 0; ni < 4; ++ni) {
                acc[mi][ni] = __builtin_amdgcn_mfma_f32_16x16x32_bf16(
                    af0[mi], bf0[ni], acc[mi][ni], 0, 0, 0);
                acc[mi][ni] = __builtin_amdgcn_mfma_f32_16x16x32_bf16(
                    af1[mi], bf1[ni], acc[mi][ni], 0, 0, 0);
            }
    }
    __syncthreads();   // drains tail prefetch (buf 0)

    // tail stage: h=0 half = X cols 768..799 -> acc
    {
        bf16x8 af[4], bfr[4];
        #pragma unroll
        for (int mi = 0; mi < 4; ++mi)
            af[mi] = *(const bf16x8*)&As[(wy * 64 + mi * 16 + l15) * 64 + pos0];
        #pragma unroll
        for (int ni = 0; ni < 4; ++ni)
            bfr[ni] = *(const bf16x8*)&Bs[(wx * 64 + ni * 16 + l15) * 64 + pos0];
        #pragma unroll
        for (int mi = 0; mi < 4; ++mi)
            #pragma unroll
            for (int ni = 0; ni < 4; ++ni)
                acc[mi][ni] = __builtin_amdgcn_mfma_f32_16x16x32_bf16(
                    af[mi], bfr[ni], acc[mi][ni], 0, 0, 0);
    }

    // Epilogue. C/D layout: col = lane&15, row = quad*4 + reg  [m89/m91]
    // E-gram (h=1 half of tail buffer) streamed per mi.
    const int slot_r = bj * 2 + wx;
    const int slot_c = bi * 2 + wy;
    bf16x8 bfrE[4];
    #pragma unroll
    for (int ni = 0; ni < 4; ++ni)
        bfrE[ni] = *(const bf16x8*)&Bs[(wx * 64 + ni * 16 + l15) * 64 + pos1];
    float cH[4] = {0,0,0,0}, cH2[4] = {0,0,0,0}, cL[4] = {0,0,0,0},
          cL2[4] = {0,0,0,0}, cHL[4] = {0,0,0,0};
    #pragma unroll
    for (int mi = 0; mi < 4; ++mi) {
        bf16x8 afE = *(const bf16x8*)&As[(wy * 64 + mi * 16 + l15) * 64 + pos1];
        f32x4 aE[4];
        #pragma unroll
        for (int ni = 0; ni < 4; ++ni) {
            f32x4 z = (f32x4){0.f, 0.f, 0.f, 0.f};
            aE[ni] = __builtin_amdgcn_mfma_f32_16x16x32_bf16(afE, bfrE[ni], z, 0, 0, 0);
        }
        const int ilocb = wy * 64 + mi * 16 + quad * 4;
        float sH[4] = {0,0,0,0}, sH2[4] = {0,0,0,0}, sL[4] = {0,0,0,0},
              sL2[4] = {0,0,0,0}, sHL[4] = {0,0,0,0};
        #pragma unroll
        for (int ni = 0; ni < 4; ++ni) {
            const int jloc = wx * 64 + ni * 16 + l15;
            const int j = j0 + jloc;
            const float sqxj = sqxs[128 + jloc];
            const float sqej = sqes[128 + jloc];
            #pragma unroll
            for (int r = 0; r < 4; ++r) {
                const int iloc = ilocb + r;
                const int i = i0 + iloc;
                float H, L;
                if (i == j) { H = 0.f; L = 0.f; }
                else {
                    float d2  = sqxs[iloc] + sqxj - 2.0f * acc[mi][ni][r];
                    H = sqrtf(fmaxf(d2, 0.f));
                    float d2e = sqes[iloc] + sqej - 2.0f * aE[ni][r];
                    L = sqrtf(fmaxf(d2e, 0.f));
                }
                sH[r] += H; sH2[r] += H * H; sL[r] += L; sL2[r] += L * L; sHL[r] += H * L;
                cH[ni] += H; cH2[ni] += H * H; cL[ni] += L; cL2[ni] += L * L; cHL[ni] += H * L;
            }
        }
        #pragma unroll
        for (int r = 0; r < 4; ++r) {
            float v0 = sH[r], v1 = sH2[r], v2 = sL[r], v3 = sL2[r], v4 = sHL[r];
            #pragma unroll
            for (int off2 = 1; off2 < 16; off2 <<= 1) {   // reduce over l15
                v0 += __shfl_xor(v0, off2, 64);
                v1 += __shfl_xor(v1, off2, 64);
                v2 += __shfl_xor(v2, off2, 64);
                v3 += __shfl_xor(v3, off2, 64);
                v4 += __shfl_xor(v4, off2, 64);
            }
            if (l15 == 0) {
                const int i = i0 + ilocb + r;
                float* base = statsp + (size_t)slot_r * NB + i;   // [c][slot][i]
                base[0 * SLAB] = v0;
                base[1 * SLAB] = v1;
                base[2 * SLAB] = v2;
                base[3 * SLAB] = v3;
                base[4 * SLAB] = v4;
            }
        }
    }
    if (bi != bj) {
        #pragma unroll
        for (int ni = 0; ni < 4; ++ni) {
            float v0 = cH[ni], v1 = cH2[ni], v2 = cL[ni], v3 = cL2[ni], v4 = cHL[ni];
            #pragma unroll
            for (int off2 = 16; off2 < 64; off2 <<= 1) {   // reduce over quad
                v0 += __shfl_xor(v0, off2, 64);
                v1 += __shfl_xor(v1, off2, 64);
                v2 += __shfl_xor(v2, off2, 64);
                v3 += __shfl_xor(v3, off2, 64);
                v4 += __shfl_xor(v4, off2, 64);
            }
            if (quad == 0) {
                const int j = j0 + wx * 64 + ni * 16 + l15;
                float* base = statsp + (size_t)slot_c * NB + j;
                base[0 * SLAB] = v0;
                base[1 * SLAB] = v1;
                base[2 * SLAB] = v2;
                base[3 * SLAB] = v3;
                base[4 * SLAB] = v4;
            }
        }
    }
}

// ---- finish1: reduce 64 slots per row, per-row corr; last block folds partials -> out
__global__ void finish1_kernel(const float* __restrict__ statsp, const float* __restrict__ upart,
                               float* __restrict__ cpart, unsigned* __restrict__ cnt,
                               float* __restrict__ out) {
    __shared__ float ps2[4][64][5];
    const int t = threadIdx.x;
    const int rloc = t & 63;
    const int sg = t >> 6;
    const int r = blockIdx.x * 64 + rloc;
    float sh = 0.f, sh2 = 0.f, sl = 0.f, sl2 = 0.f, shl = 0.f;
    for (int s = sg * 16; s < sg * 16 + 16; ++s) {
        const float* base = statsp + (size_t)s * NB + r;
        sh  += base[0 * SLAB];
        sh2 += base[1 * SLAB];
        sl  += base[2 * SLAB];
        sl2 += base[3 * SLAB];
        shl += base[4 * SLAB];
    }
    ps2[sg][rloc][0] = sh; ps2[sg][rloc][1] = sh2; ps2[sg][rloc][2] = sl;
    ps2[sg][rloc][3] = sl2; ps2[sg][rloc][4] = shl;
    __syncthreads();
    if (t < 64) {
        float a = 0.f, b = 0.f, c = 0.f, d = 0.f, e = 0.f;
        #pragma unroll
        for (int g = 0; g < 4; ++g) {
            a += ps2[g][t][0]; b += ps2[g][t][1]; c += ps2[g][t][2];
            d += ps2[g][t][3]; e += ps2[g][t][4];
        }
        const float invN = 1.0f / (float)NB;
        float num = e - a * c * invN;
        float vh  = fmaxf(b - a * a * invN, 0.f);
        float vl  = fmaxf(d - c * c * invN, 0.f);
        float local = num / (sqrtf(vh) * sqrtf(vl));
        #pragma unroll
        for (int off = 32; off; off >>= 1) local += __shfl_down(local, off, 64);
        if (t == 0) cpart[blockIdx.x] = local;
    }
    // last block folds 64 corr partials + 96 umap partials into the loss
    __shared__ int lastFlag;
    if (t == 0) {
        __threadfence();                       // cpart store visible device-wide
        unsigned prev = atomicAdd(cnt, 1u);
        lastFlag = (prev == 63u);
    }
    __syncthreads();
    if (lastFlag) {
        __threadfence();                       // acquire other blocks' cpart
        float v = 0.f;
        if (t < 64) v += cpart[t] * (-BETA_C / (float)NB);
        if (t < 96) v += upart[t] * (ALPHA_C / (float)NTOT);
        #pragma unroll
        for (int off = 32; off; off >>= 1) v += __shfl_down(v, off, 64);
        __shared__ float fin[4];
        if ((t & 63) == 0) fin[t >> 6] = v;
        __syncthreads();
        if (t == 0) out[0] = fin[0] + fin[1] + fin[2] + fin[3];
    }
}

extern "C" void kernel_launch(void* const* d_in, const int* in_sizes, int n_in,
                              void* d_out, int out_size, void* d_ws, size_t ws_size,
                              hipStream_t stream) {
    const float* emb  = (const float*)d_in[0];   // (4096, 32) f32
    const float* ph   = (const float*)d_in[1];   // (4096, 784) f32
    const int*   perm = (const int*)d_in[2];     // (20480,) i32
    float* out = (float*)d_out;

    char* ws = (char*)d_ws;
    bf16*  Xbf    = (bf16*) (ws + WS_XBF);
    bf16*  Ebf    = (bf16*) (ws + WS_EBF);
    float* sqx    = (float*)(ws + WS_SQX);
    float* sqe    = (float*)(ws + WS_SQE);
    float* statsp = (float*)(ws + WS_STATSP);
    float* upart  = (float*)(ws + WS_UPART);
    float* cpart  = (float*)(ws + WS_CPART);
    unsigned* cnt = (unsigned*)(ws + WS_CNT);

    prep_fused<<<1120, 256, 0, stream>>>(ph, emb, perm, Xbf, sqx, Ebf, sqe, upart, cnt);
    gram_kernel<<<NBLK, 256, 0, stream>>>(Xbf, Ebf, sqx, sqe, statsp);
    finish1_kernel<<<64, 256, 0, stream>>>(statsp, upart, cpart, cnt, out);
}

// Round 6
// 120.213 us; speedup vs baseline: 1.1200x; 1.1200x over previous
//
#include <hip/hip_runtime.h>
#include <hip/hip_bf16.h>
#include <math.h>

// Problem constants
#define NB    4096
#define DH    784
#define KX8   832            // fp8 row bytes: 784 padded to 13*64
#define NSR   5
#define NNEG  (NB*NSR)       // 20480
#define NTOT  (NB + NNEG)    // 24576

#define A_CONST 1.576943f
#define PEXP    1.7901216f   // 2*B_PARAM
#define EPS_C   1.0e-4f
#define ALPHA_C 0.9296875f   // BATCH_COUNT=500: beta=0.5*(1-500/800)^2=0.0703125
#define BETA_C  0.0703125f

#define NSLOT 64             // per row: 32 block-contribs x 2 wave-halves
#define SLAB  (NB * NSLOT)   // elements per stat component = 262144
#define NBLK  528            // upper-triangular 32x32 block grid (8*66)
#define BUFB  8192           // LDS buffer stride in BYTES (128 rows x 64 B)

typedef __hip_bfloat16 bf16;
typedef short bf16x8 __attribute__((ext_vector_type(8)));
typedef float f32x4  __attribute__((ext_vector_type(4)));

// Workspace layout (bytes)
#define WS_XF8    0                      // 4096*832   = 3407872
#define WS_EBF    3407872                // 4096*32*2  = 262144
#define WS_SQX    3670016                // 4096*4     = 16384
#define WS_SQE    3686400                // 4096*4     = 16384
#define WS_STATSP 3702784                // 5*262144*4 = 5242880
#define WS_UPART  8945664                // 96*4       = 384
#define WS_CPART  8946048                // 64*4       = 256
#define WS_CNT    8946304                // 4

__device__ __forceinline__ void gl2lds16(const void* g, void* l) {
    __builtin_amdgcn_global_load_lds(
        (const __attribute__((address_space(1))) unsigned int*)g,
        (__attribute__((address_space(3))) unsigned int*)l,
        16, 0, 0);
}

// ---- fused prep: blocks 0..1023 -> X cast to fp8-e4m3 (pad to 832B) + sqnorm;
//                  blocks 1024..1119 -> UMAP CE partials + e_to bf16 prep
__global__ void prep_fused(const float* __restrict__ X, const float* __restrict__ emb,
                           const int* __restrict__ perm, unsigned char* __restrict__ Xf8,
                           float* __restrict__ sqx, bf16* __restrict__ Ebf,
                           float* __restrict__ sqe, float* __restrict__ upart,
                           unsigned* __restrict__ cnt) {
    if (blockIdx.x == 0 && threadIdx.x == 0) *cnt = 0u;   // for finish1 last-block
    if (blockIdx.x < 1024) {
        // one row per wave; 196 float4 in, 208 packed-fp8 dwords out
        const int wave = threadIdx.x >> 6, lane = threadIdx.x & 63;
        const int row = blockIdx.x * 4 + wave;
        const float4* xr = (const float4*)(X + (size_t)row * DH);
        int* xb = (int*)(Xf8 + (size_t)row * KX8);
        float s = 0.f;
        #pragma unroll
        for (int it = 0; it < 4; ++it) {
            const int idx = lane + it * 64;
            if (idx < 196) {
                float4 v = xr[idx];
                s += v.x * v.x + v.y * v.y + v.z * v.z + v.w * v.w;
                int lo = __builtin_amdgcn_cvt_pk_fp8_f32(v.x, v.y, 0, false);
                int pk = __builtin_amdgcn_cvt_pk_fp8_f32(v.z, v.w, lo, true);
                xb[idx] = pk;
            } else if (idx < 208) {
                xb[idx] = 0;                  // pad bytes 784..831
            }
        }
        #pragma unroll
        for (int off = 32; off; off >>= 1) s += __shfl_down(s, off, 64);
        if (lane == 0) sqx[row] = s;
        return;
    }
    // UMAP CE + e_to bf16 prep
    const int ub = blockIdx.x - 1024;
    const int t = ub * 256 + threadIdx.x;
    float val = 0.f;
    if (t < NB) {
        const float4* av = (const float4*)(emb + (size_t)t * 32);
        float4 t0 = av[0], t1 = av[1], t2 = av[2], t3 = av[3];   // e_to
        float4 f0 = av[4], f1 = av[5], f2 = av[6], f3 = av[7];   // e_from
        bf16* eb = Ebf + (size_t)t * 32;
        union { bf16 h[4]; ushort4 u; } cv;
        #define ST4(dst, q) cv.h[0]=__float2bfloat16(q.x); cv.h[1]=__float2bfloat16(q.y); \
                            cv.h[2]=__float2bfloat16(q.z); cv.h[3]=__float2bfloat16(q.w); \
                            *(ushort4*)(dst) = cv.u;
        ST4(eb,      t0) ST4(eb + 4,  t1) ST4(eb + 8,  t2) ST4(eb + 12, t3)
        #undef ST4
        ushort4 z = {0, 0, 0, 0};
        *(ushort4*)(eb + 16) = z; *(ushort4*)(eb + 20) = z;
        *(ushort4*)(eb + 24) = z; *(ushort4*)(eb + 28) = z;
        sqe[t] = t0.x*t0.x + t0.y*t0.y + t0.z*t0.z + t0.w*t0.w
               + t1.x*t1.x + t1.y*t1.y + t1.z*t1.z + t1.w*t1.w
               + t2.x*t2.x + t2.y*t2.y + t2.z*t2.z + t2.w*t2.w
               + t3.x*t3.x + t3.y*t3.y + t3.z*t3.z + t3.w*t3.w;
        float d2 = 0.f;
        #define D2(a, b) { float4 df = {a.x-b.x, a.y-b.y, a.z-b.z, a.w-b.w}; \
                           d2 += df.x*df.x + df.y*df.y + df.z*df.z + df.w*df.w; }
        D2(t0, f0) D2(t1, f1) D2(t2, f2) D2(t3, f3)
        #undef D2
        float d = sqrtf(d2);
        float p = 1.f / (1.f + A_CONST * powf(d, PEXP));
        val = -logf(fminf(fmaxf(p, EPS_C), 1.f));
    } else if (t < NTOT) {
        const int k = t - NB;
        const int ti = k / 5;
        const int fi = perm[k] / 5;
        const float4* at = (const float4*)(emb + (size_t)ti * 32);
        const float4* bt = (const float4*)(emb + (size_t)fi * 32 + 16);
        float d2 = 0.f;
        #pragma unroll
        for (int q = 0; q < 4; ++q) {
            float4 a = at[q], b = bt[q];
            float4 df = {a.x-b.x, a.y-b.y, a.z-b.z, a.w-b.w};
            d2 += df.x*df.x + df.y*df.y + df.z*df.z + df.w*df.w;
        }
        float d = sqrtf(d2);
        float p = 1.f / (1.f + A_CONST * powf(d, PEXP));
        val = -logf(fminf(fmaxf(1.f - p, EPS_C), 1.f));
    }
    #pragma unroll
    for (int off = 32; off; off >>= 1) val += __shfl_down(val, off, 64);
    __shared__ float ps[4];
    if ((threadIdx.x & 63) == 0) ps[threadIdx.x >> 6] = val;
    __syncthreads();
    if (threadIdx.x == 0) upart[ub] = ps[0] + ps[1] + ps[2] + ps[3];
}

// ---- main: upper-triangular 128x128 X-gram in fp8-e4m3 (13 stages of 64-B rows,
// double-buffered, R4 geometry) + bf16 E-gram tail + symmetric stats epilogue.
// LDS[r][p] (16-B segs) holds global seg p^((r>>1)&3): even bank spread for
// fp8 b64 frags, bf16 b128 frags, and 16-B coalesced staging.
__global__ __launch_bounds__(256, 3) void gram_kernel(
    const unsigned char* __restrict__ Xf8, const bf16* __restrict__ Ebf,
    const float* __restrict__ sqx, const float* __restrict__ sqe,
    float* __restrict__ statsp) {
    __shared__ unsigned char As[2 * BUFB];   // 16 KB (double-buffered 128 x 64 B)
    __shared__ unsigned char Bs[2 * BUFB];   // 16 KB
    __shared__ float sqxs[256];              // [0..127]=i rows, [128..255]=j cols
    __shared__ float sqes[256];

    // XCD swizzle: 528 = 8*66; XCD k gets 66 consecutive triangle entries.
    int n = (blockIdx.x & 7) * 66 + (blockIdx.x >> 3);
    int bi = 0;
    while (n >= 32 - bi) { n -= 32 - bi; ++bi; }
    const int bj = bi + n;
    const int i0 = bi * 128, j0 = bj * 128;

    const int tid  = threadIdx.x;
    const int wave = tid >> 6;
    const int lane = tid & 63;
    const int wy = wave >> 1, wx = wave & 1;
    const int quad = lane >> 4, l15 = lane & 15;

    f32x4 acc[4][4];
    #pragma unroll
    for (int a = 0; a < 4; ++a)
        #pragma unroll
        for (int b = 0; b < 4; ++b)
            acc[a][b] = (f32x4){0.f, 0.f, 0.f, 0.f};

    // staging: 8 chunks of 16 rows; wave stages chunks {2w,2w+1}.
    // lane L: row chunk*16 + (L>>2); global 16-B seg (L&3)^((L>>3)&3).
    const int c0  = wave * 2;
    const int rA  = lane >> 2;
    const int gsb = (((lane & 3) ^ ((lane >> 3) & 3))) * 16;   // byte offset

    const unsigned char* gA0 = Xf8 + (size_t)(i0 + c0 * 16 + rA) * KX8 + gsb;
    const unsigned char* gA1 = Xf8 + (size_t)(i0 + c0 * 16 + 16 + rA) * KX8 + gsb;
    const unsigned char* gB0 = Xf8 + (size_t)(j0 + c0 * 16 + rA) * KX8 + gsb;
    const unsigned char* gB1 = Xf8 + (size_t)(j0 + c0 * 16 + 16 + rA) * KX8 + gsb;

    // prologue: prefetch stage 0 into buf 0
    gl2lds16(gA0, As + c0 * 1024);
    gl2lds16(gA1, As + c0 * 1024 + 1024);
    gl2lds16(gB0, Bs + c0 * 1024);
    gl2lds16(gB1, Bs + c0 * 1024 + 1024);
    gA0 += 64; gA1 += 64; gB0 += 64; gB1 += 64;

    if (tid < 128) {
        sqxs[tid] = sqx[i0 + tid]; sqxs[128 + tid] = sqx[j0 + tid];
        sqes[tid] = sqe[i0 + tid]; sqes[128 + tid] = sqe[j0 + tid];
    }

    // fp8 fragment byte offsets within a 64-B row (K-half h, seg s=2h+(quad>>1),
    // stored at pos s^key, +8B for odd quad):
    const int key = (l15 >> 1) & 3;
    const int bo0 = (((quad >> 1) ^ key) << 4)       + (quad & 1) * 8;   // h=0
    const int bo1 = (((2 + (quad >> 1)) ^ key) << 4) + (quad & 1) * 8;   // h=1
    // bf16 E fragment (seg = quad): 16-B read at pos quad^key
    const int boE = ((quad ^ key) << 4);

    for (int t = 0; t < 13; ++t) {
        __syncthreads();                       // drains prefetch of buf[t&1]
        const int cur = (t & 1) * BUFB;
        const int nb  = ((t + 1) & 1) * BUFB;
        if (t < 12) {                          // prefetch next 64-B K-slice
            gl2lds16(gA0, As + nb + c0 * 1024);
            gl2lds16(gA1, As + nb + c0 * 1024 + 1024);
            gl2lds16(gB0, Bs + nb + c0 * 1024);
            gl2lds16(gB1, Bs + nb + c0 * 1024 + 1024);
            gA0 += 64; gA1 += 64; gB0 += 64; gB1 += 64;
        } else {                               // t==12: prefetch E (64-B rows) into buf 1
            gl2lds16((const unsigned char*)(Ebf + (size_t)(i0 + c0 * 16 + rA) * 32) + gsb,
                     As + nb + c0 * 1024);
            gl2lds16((const unsigned char*)(Ebf + (size_t)(i0 + c0 * 16 + 16 + rA) * 32) + gsb,
                     As + nb + c0 * 1024 + 1024);
            gl2lds16((const unsigned char*)(Ebf + (size_t)(j0 + c0 * 16 + rA) * 32) + gsb,
                     Bs + nb + c0 * 1024);
            gl2lds16((const unsigned char*)(Ebf + (size_t)(j0 + c0 * 16 + 16 + rA) * 32) + gsb,
                     Bs + nb + c0 * 1024 + 1024);
        }
        long a0[4], a1[4], b0[4], b1[4];
        #pragma unroll
        for (int mi = 0; mi < 4; ++mi) {
            const int r = cur + (wy * 64 + mi * 16 + l15) * 64;
            a0[mi] = *(const long*)&As[r + bo0];
            a1[mi] = *(const long*)&As[r + bo1];
        }
        #pragma unroll
        for (int ni = 0; ni < 4; ++ni) {
            const int r = cur + (wx * 64 + ni * 16 + l15) * 64;
            b0[ni] = *(const long*)&Bs[r + bo0];
            b1[ni] = *(const long*)&Bs[r + bo1];
        }
        #pragma unroll
        for (int mi = 0; mi < 4; ++mi)
            #pragma unroll
            for (int ni = 0; ni < 4; ++ni) {
                acc[mi][ni] = __builtin_amdgcn_mfma_f32_16x16x32_fp8_fp8(
                    a0[mi], b0[ni], acc[mi][ni], 0, 0, 0);
                acc[mi][ni] = __builtin_amdgcn_mfma_f32_16x16x32_fp8_fp8(
                    a1[mi], b1[ni], acc[mi][ni], 0, 0, 0);
            }
    }
    __syncthreads();   // drains E prefetch (buf 1)

    // Epilogue. C/D layout: col = lane&15, row = quad*4 + reg  [m89/m91]
    // E-gram (bf16, buf 1) streamed per mi to cap register pressure.
    const int slot_r = bj * 2 + wx;
    const int slot_c = bi * 2 + wy;
    bf16x8 bfrE[4];
    #pragma unroll
    for (int ni = 0; ni < 4; ++ni)
        bfrE[ni] = *(const bf16x8*)&Bs[BUFB + (wx * 64 + ni * 16 + l15) * 64 + boE];
    float cH[4] = {0,0,0,0}, cH2[4] = {0,0,0,0}, cL[4] = {0,0,0,0},
          cL2[4] = {0,0,0,0}, cHL[4] = {0,0,0,0};
    #pragma unroll
    for (int mi = 0; mi < 4; ++mi) {
        bf16x8 afE = *(const bf16x8*)&As[BUFB + (wy * 64 + mi * 16 + l15) * 64 + boE];
        f32x4 aE[4];
        #pragma unroll
        for (int ni = 0; ni < 4; ++ni) {
            f32x4 z = (f32x4){0.f, 0.f, 0.f, 0.f};
            aE[ni] = __builtin_amdgcn_mfma_f32_16x16x32_bf16(afE, bfrE[ni], z, 0, 0, 0);
        }
        const int ilocb = wy * 64 + mi * 16 + quad * 4;
        float sH[4] = {0,0,0,0}, sH2[4] = {0,0,0,0}, sL[4] = {0,0,0,0},
              sL2[4] = {0,0,0,0}, sHL[4] = {0,0,0,0};
        #pragma unroll
        for (int ni = 0; ni < 4; ++ni) {
            const int jloc = wx * 64 + ni * 16 + l15;
            const int j = j0 + jloc;
            const float sqxj = sqxs[128 + jloc];
            const float sqej = sqes[128 + jloc];
            #pragma unroll
            for (int r = 0; r < 4; ++r) {
                const int iloc = ilocb + r;
                const int i = i0 + iloc;
                float H, L;
                if (i == j) { H = 0.f; L = 0.f; }
                else {
                    float d2  = sqxs[iloc] + sqxj - 2.0f * acc[mi][ni][r];
                    H = sqrtf(fmaxf(d2, 0.f));
                    float d2e = sqes[iloc] + sqej - 2.0f * aE[ni][r];
                    L = sqrtf(fmaxf(d2e, 0.f));
                }
                sH[r] += H; sH2[r] += H * H; sL[r] += L; sL2[r] += L * L; sHL[r] += H * L;
                cH[ni] += H; cH2[ni] += H * H; cL[ni] += L; cL2[ni] += L * L; cHL[ni] += H * L;
            }
        }
        #pragma unroll
        for (int r = 0; r < 4; ++r) {
            float v0 = sH[r], v1 = sH2[r], v2 = sL[r], v3 = sL2[r], v4 = sHL[r];
            #pragma unroll
            for (int off2 = 1; off2 < 16; off2 <<= 1) {   // reduce over l15
                v0 += __shfl_xor(v0, off2, 64);
                v1 += __shfl_xor(v1, off2, 64);
                v2 += __shfl_xor(v2, off2, 64);
                v3 += __shfl_xor(v3, off2, 64);
                v4 += __shfl_xor(v4, off2, 64);
            }
            if (l15 == 0) {
                const int i = i0 + ilocb + r;
                float* base = statsp + (size_t)slot_r * NB + i;   // [c][slot][i]
                base[0 * SLAB] = v0;
                base[1 * SLAB] = v1;
                base[2 * SLAB] = v2;
                base[3 * SLAB] = v3;
                base[4 * SLAB] = v4;
            }
        }
    }
    if (bi != bj) {
        #pragma unroll
        for (int ni = 0; ni < 4; ++ni) {
            float v0 = cH[ni], v1 = cH2[ni], v2 = cL[ni], v3 = cL2[ni], v4 = cHL[ni];
            #pragma unroll
            for (int off2 = 16; off2 < 64; off2 <<= 1) {   // reduce over quad
                v0 += __shfl_xor(v0, off2, 64);
                v1 += __shfl_xor(v1, off2, 64);
                v2 += __shfl_xor(v2, off2, 64);
                v3 += __shfl_xor(v3, off2, 64);
                v4 += __shfl_xor(v4, off2, 64);
            }
            if (quad == 0) {
                const int j = j0 + wx * 64 + ni * 16 + l15;
                float* base = statsp + (size_t)slot_c * NB + j;
                base[0 * SLAB] = v0;
                base[1 * SLAB] = v1;
                base[2 * SLAB] = v2;
                base[3 * SLAB] = v3;
                base[4 * SLAB] = v4;
            }
        }
    }
}

// ---- finish1: reduce 64 slots per row, per-row corr; last block folds partials -> out
__global__ void finish1_kernel(const float* __restrict__ statsp, const float* __restrict__ upart,
                               float* __restrict__ cpart, unsigned* __restrict__ cnt,
                               float* __restrict__ out) {
    __shared__ float ps2[4][64][5];
    const int t = threadIdx.x;
    const int rloc = t & 63;
    const int sg = t >> 6;
    const int r = blockIdx.x * 64 + rloc;
    float sh = 0.f, sh2 = 0.f, sl = 0.f, sl2 = 0.f, shl = 0.f;
    for (int s = sg * 16; s < sg * 16 + 16; ++s) {
        const float* base = statsp + (size_t)s * NB + r;
        sh  += base[0 * SLAB];
        sh2 += base[1 * SLAB];
        sl  += base[2 * SLAB];
        sl2 += base[3 * SLAB];
        shl += base[4 * SLAB];
    }
    ps2[sg][rloc][0] = sh; ps2[sg][rloc][1] = sh2; ps2[sg][rloc][2] = sl;
    ps2[sg][rloc][3] = sl2; ps2[sg][rloc][4] = shl;
    __syncthreads();
    if (t < 64) {
        float a = 0.f, b = 0.f, c = 0.f, d = 0.f, e = 0.f;
        #pragma unroll
        for (int g = 0; g < 4; ++g) {
            a += ps2[g][t][0]; b += ps2[g][t][1]; c += ps2[g][t][2];
            d += ps2[g][t][3]; e += ps2[g][t][4];
        }
        const float invN = 1.0f / (float)NB;
        float num = e - a * c * invN;
        float vh  = fmaxf(b - a * a * invN, 0.f);
        float vl  = fmaxf(d - c * c * invN, 0.f);
        float local = num / (sqrtf(vh) * sqrtf(vl));
        #pragma unroll
        for (int off = 32; off; off >>= 1) local += __shfl_down(local, off, 64);
        if (t == 0) cpart[blockIdx.x] = local;
    }
    // last block folds 64 corr partials + 96 umap partials into the loss
    __shared__ int lastFlag;
    if (t == 0) {
        __threadfence();                       // cpart store visible device-wide
        unsigned prev = atomicAdd(cnt, 1u);
        lastFlag = (prev == 63u);
    }
    __syncthreads();
    if (lastFlag) {
        __threadfence();                       // acquire other blocks' cpart
        float v = 0.f;
        if (t < 64) v += cpart[t] * (-BETA_C / (float)NB);
        if (t < 96) v += upart[t] * (ALPHA_C / (float)NTOT);
        #pragma unroll
        for (int off = 32; off; off >>= 1) v += __shfl_down(v, off, 64);
        __shared__ float fin[4];
        if ((t & 63) == 0) fin[t >> 6] = v;
        __syncthreads();
        if (t == 0) out[0] = fin[0] + fin[1] + fin[2] + fin[3];
    }
}

extern "C" void kernel_launch(void* const* d_in, const int* in_sizes, int n_in,
                              void* d_out, int out_size, void* d_ws, size_t ws_size,
                              hipStream_t stream) {
    const float* emb  = (const float*)d_in[0];   // (4096, 32) f32
    const float* ph   = (const float*)d_in[1];   // (4096, 784) f32
    const int*   perm = (const int*)d_in[2];     // (20480,) i32
    float* out = (float*)d_out;

    char* ws = (char*)d_ws;
    unsigned char* Xf8 = (unsigned char*)(ws + WS_XF8);
    bf16*  Ebf    = (bf16*) (ws + WS_EBF);
    float* sqx    = (float*)(ws + WS_SQX);
    float* sqe    = (float*)(ws + WS_SQE);
    float* statsp = (float*)(ws + WS_STATSP);
    float* upart  = (float*)(ws + WS_UPART);
    float* cpart  = (float*)(ws + WS_CPART);
    unsigned* cnt = (unsigned*)(ws + WS_CNT);

    prep_fused<<<1120, 256, 0, stream>>>(ph, emb, perm, Xf8, sqx, Ebf, sqe, upart, cnt);
    gram_kernel<<<NBLK, 256, 0, stream>>>(Xf8, Ebf, sqx, sqe, statsp);
    finish1_kernel<<<64, 256, 0, stream>>>(statsp, upart, cpart, cnt, out);
}

// Round 7
// 118.769 us; speedup vs baseline: 1.1336x; 1.0122x over previous
//
#include <hip/hip_runtime.h>
#include <hip/hip_bf16.h>
#include <math.h>

// Problem constants
#define NB    4096
#define DH    784
#define KX8   832            // fp8 row bytes: 784 padded to 13*64
#define NSR   5
#define NNEG  (NB*NSR)       // 20480
#define NTOT  (NB + NNEG)    // 24576

#define A_CONST 1.576943f
#define PEXP    1.7901216f   // 2*B_PARAM
#define EPS_C   1.0e-4f
#define ALPHA_C 0.9296875f   // BATCH_COUNT=500: beta=0.5*(1-500/800)^2=0.0703125
#define BETA_C  0.0703125f

#define NSLOT 64             // per row: 32 block-contribs x 2 wave-halves
#define SLAB  (NB * NSLOT)   // elements per stat component = 262144
#define NBLK  528            // upper-triangular 32x32 block grid (8*66)
#define BUFB  8192           // LDS buffer stride in BYTES (128 rows x 64 B)

typedef __hip_bfloat16 bf16;
typedef short bf16x8 __attribute__((ext_vector_type(8)));
typedef float f32x4  __attribute__((ext_vector_type(4)));
typedef long long2v __attribute__((ext_vector_type(2)));

// Workspace layout (bytes)
#define WS_XF8    0                      // 4096*832   = 3407872
#define WS_EBF    3407872                // 4096*32*2  = 262144
#define WS_SQX    3670016                // 4096*4     = 16384
#define WS_SQE    3686400                // 4096*4     = 16384
#define WS_STATSP 3702784                // 5*262144*4 = 5242880
#define WS_UPART  8945664                // 96*4       = 384
#define WS_CPART  8946048                // 64*4       = 256
#define WS_CNT    8946304                // 4

__device__ __forceinline__ void gl2lds16(const void* g, void* l) {
    __builtin_amdgcn_global_load_lds(
        (const __attribute__((address_space(1))) unsigned int*)g,
        (__attribute__((address_space(3))) unsigned int*)l,
        16, 0, 0);
}

// ---- fused prep: blocks 0..1023 -> X cast to fp8-e4m3, COLUMN-PERMUTED layout
// (each 64B chunk stored as [q0h0|q0h1|q1h0|q1h1|...]: dest dword p in chunk c
// sources src float4 c*16 + h*8 + q*2 + w, q=p>>2, h=(p>>1)&1, w=p&1), + sqnorm;
// blocks 1024..1119 -> UMAP CE partials + e_to bf16 prep
__global__ void prep_fused(const float* __restrict__ X, const float* __restrict__ emb,
                           const int* __restrict__ perm, unsigned char* __restrict__ Xf8,
                           float* __restrict__ sqx, bf16* __restrict__ Ebf,
                           float* __restrict__ sqe, float* __restrict__ upart,
                           unsigned* __restrict__ cnt) {
    if (blockIdx.x == 0 && threadIdx.x == 0) *cnt = 0u;   // for finish1 last-block
    if (blockIdx.x < 1024) {
        const int wave = threadIdx.x >> 6, lane = threadIdx.x & 63;
        const int row = blockIdx.x * 4 + wave;
        const float4* xr = (const float4*)(X + (size_t)row * DH);
        int* xb = (int*)(Xf8 + (size_t)row * KX8);
        float s = 0.f;
        #pragma unroll
        for (int it = 0; it < 4; ++it) {
            const int idx = lane + it * 64;   // dest dword 0..207
            if (idx < 208) {
                const int c = idx >> 4, p = idx & 15;
                const int q = p >> 2, h = (p >> 1) & 1, w = p & 1;
                const int src = c * 16 + h * 8 + q * 2 + w;
                int pk = 0;
                if (src < 196) {
                    float4 v = xr[src];
                    s += v.x * v.x + v.y * v.y + v.z * v.z + v.w * v.w;
                    int lo = __builtin_amdgcn_cvt_pk_fp8_f32(v.x, v.y, 0, false);
                    pk = __builtin_amdgcn_cvt_pk_fp8_f32(v.z, v.w, lo, true);
                }
                xb[idx] = pk;
            }
        }
        #pragma unroll
        for (int off = 32; off; off >>= 1) s += __shfl_down(s, off, 64);
        if (lane == 0) sqx[row] = s;
        return;
    }
    // UMAP CE + e_to bf16 prep
    const int ub = blockIdx.x - 1024;
    const int t = ub * 256 + threadIdx.x;
    float val = 0.f;
    if (t < NB) {
        const float4* av = (const float4*)(emb + (size_t)t * 32);
        float4 t0 = av[0], t1 = av[1], t2 = av[2], t3 = av[3];   // e_to
        float4 f0 = av[4], f1 = av[5], f2 = av[6], f3 = av[7];   // e_from
        bf16* eb = Ebf + (size_t)t * 32;
        union { bf16 h[4]; ushort4 u; } cv;
        #define ST4(dst, q) cv.h[0]=__float2bfloat16(q.x); cv.h[1]=__float2bfloat16(q.y); \
                            cv.h[2]=__float2bfloat16(q.z); cv.h[3]=__float2bfloat16(q.w); \
                            *(ushort4*)(dst) = cv.u;
        ST4(eb,      t0) ST4(eb + 4,  t1) ST4(eb + 8,  t2) ST4(eb + 12, t3)
        #undef ST4
        ushort4 z = {0, 0, 0, 0};
        *(ushort4*)(eb + 16) = z; *(ushort4*)(eb + 20) = z;
        *(ushort4*)(eb + 24) = z; *(ushort4*)(eb + 28) = z;
        sqe[t] = t0.x*t0.x + t0.y*t0.y + t0.z*t0.z + t0.w*t0.w
               + t1.x*t1.x + t1.y*t1.y + t1.z*t1.z + t1.w*t1.w
               + t2.x*t2.x + t2.y*t2.y + t2.z*t2.z + t2.w*t2.w
               + t3.x*t3.x + t3.y*t3.y + t3.z*t3.z + t3.w*t3.w;
        float d2 = 0.f;
        #define D2(a, b) { float4 df = {a.x-b.x, a.y-b.y, a.z-b.z, a.w-b.w}; \
                           d2 += df.x*df.x + df.y*df.y + df.z*df.z + df.w*df.w; }
        D2(t0, f0) D2(t1, f1) D2(t2, f2) D2(t3, f3)
        #undef D2
        float d = sqrtf(d2);
        float p = 1.f / (1.f + A_CONST * powf(d, PEXP));
        val = -logf(fminf(fmaxf(p, EPS_C), 1.f));
    } else if (t < NTOT) {
        const int k = t - NB;
        const int ti = k / 5;
        const int fi = perm[k] / 5;
        const float4* at = (const float4*)(emb + (size_t)ti * 32);
        const float4* bt = (const float4*)(emb + (size_t)fi * 32 + 16);
        float d2 = 0.f;
        #pragma unroll
        for (int q = 0; q < 4; ++q) {
            float4 a = at[q], b = bt[q];
            float4 df = {a.x-b.x, a.y-b.y, a.z-b.z, a.w-b.w};
            d2 += df.x*df.x + df.y*df.y + df.z*df.z + df.w*df.w;
        }
        float d = sqrtf(d2);
        float p = 1.f / (1.f + A_CONST * powf(d, PEXP));
        val = -logf(fminf(fmaxf(1.f - p, EPS_C), 1.f));
    }
    #pragma unroll
    for (int off = 32; off; off >>= 1) val += __shfl_down(val, off, 64);
    __shared__ float ps[4];
    if ((threadIdx.x & 63) == 0) ps[threadIdx.x >> 6] = val;
    __syncthreads();
    if (threadIdx.x == 0) upart[ub] = ps[0] + ps[1] + ps[2] + ps[3];
}

// ---- main: upper-triangular 128x128 fp8 X-gram, TRIPLE-buffered depth-2
// prefetch pipeline with fine-grained `s_waitcnt vmcnt(4)` + raw s_barrier
// (never drains in-flight prefetches), column-permuted layout -> one
// conflict-free ds_read_b128 per fragment (both K-halves), bf16 E-gram tail.
__global__ __launch_bounds__(256, 3) void gram_kernel(
    const unsigned char* __restrict__ Xf8, const bf16* __restrict__ Ebf,
    const float* __restrict__ sqx, const float* __restrict__ sqe,
    float* __restrict__ statsp) {
    __shared__ unsigned char As[3 * BUFB];   // 24 KB
    __shared__ unsigned char Bs[3 * BUFB];   // 24 KB
    __shared__ float sqxs[256];              // [0..127]=i rows, [128..255]=j cols
    __shared__ float sqes[256];

    // XCD swizzle: 528 = 8*66; XCD k gets 66 consecutive triangle entries.
    int n = (blockIdx.x & 7) * 66 + (blockIdx.x >> 3);
    int bi = 0;
    while (n >= 32 - bi) { n -= 32 - bi; ++bi; }
    const int bj = bi + n;
    const int i0 = bi * 128, j0 = bj * 128;

    const int tid  = threadIdx.x;
    const int wave = tid >> 6;
    const int lane = tid & 63;
    const int wy = wave >> 1, wx = wave & 1;
    const int quad = lane >> 4, l15 = lane & 15;

    f32x4 acc[4][4];
    #pragma unroll
    for (int a = 0; a < 4; ++a)
        #pragma unroll
        for (int b = 0; b < 4; ++b)
            acc[a][b] = (f32x4){0.f, 0.f, 0.f, 0.f};

    // staging: 8 chunks of 16 rows; wave stages chunks {2w,2w+1}.
    // lane L: row chunk*16 + (L>>2); global 16-B seg (L&3)^((L>>3)&3).
    const int c0  = wave * 2;
    const int rA  = lane >> 2;
    const int gsb = (((lane & 3) ^ ((lane >> 3) & 3))) * 16;   // byte offset

    const unsigned char* gA0 = Xf8 + (size_t)(i0 + c0 * 16 + rA) * KX8 + gsb;
    const unsigned char* gA1 = Xf8 + (size_t)(i0 + c0 * 16 + 16 + rA) * KX8 + gsb;
    const unsigned char* gB0 = Xf8 + (size_t)(j0 + c0 * 16 + rA) * KX8 + gsb;
    const unsigned char* gB1 = Xf8 + (size_t)(j0 + c0 * 16 + 16 + rA) * KX8 + gsb;

    // sq-norm staging FIRST, then one full __syncthreads (its vmcnt(0) drain
    // happens before any DMA is in flight).
    if (tid < 128) {
        sqxs[tid] = sqx[i0 + tid]; sqxs[128 + tid] = sqx[j0 + tid];
        sqes[tid] = sqe[i0 + tid]; sqes[128 + tid] = sqe[j0 + tid];
    }
    __syncthreads();

    // prologue: prefetch stages 0 and 1 (buffers 0, 1)
    #pragma unroll
    for (int s = 0; s < 2; ++s) {
        gl2lds16(gA0, As + s * BUFB + c0 * 1024);
        gl2lds16(gA1, As + s * BUFB + c0 * 1024 + 1024);
        gl2lds16(gB0, Bs + s * BUFB + c0 * 1024);
        gl2lds16(gB1, Bs + s * BUFB + c0 * 1024 + 1024);
        gA0 += 64; gA1 += 64; gB0 += 64; gB1 += 64;
    }

    // fragment byte offset: 16B = [h0 8B | h1 8B] for this lane's quad
    // (column-permuted layout), at swizzled position quad^key.
    const int key = (l15 >> 1) & 3;
    const int boX = ((quad ^ key) << 4);

    int cur = 0;                      // buf byte offset of stage t
    for (int t = 0; t < 13; ++t) {
        // wait ONLY this stage's DMA (leaves stage t+1 in flight), then sync.
        asm volatile("s_waitcnt vmcnt(4)" ::: "memory");
        __builtin_amdgcn_s_barrier();
        const int nb = (cur + 2 * BUFB >= 3 * BUFB) ? cur - BUFB : cur + 2 * BUFB;
        if (t < 11) {                 // prefetch X stage t+2
            gl2lds16(gA0, As + nb + c0 * 1024);
            gl2lds16(gA1, As + nb + c0 * 1024 + 1024);
            gl2lds16(gB0, Bs + nb + c0 * 1024);
            gl2lds16(gB1, Bs + nb + c0 * 1024 + 1024);
            gA0 += 64; gA1 += 64; gB0 += 64; gB1 += 64;
        } else if (t == 11) {         // prefetch E (stage 13) into buf 1
            gl2lds16((const unsigned char*)(Ebf + (size_t)(i0 + c0 * 16 + rA) * 32) + gsb,
                     As + BUFB + c0 * 1024);
            gl2lds16((const unsigned char*)(Ebf + (size_t)(i0 + c0 * 16 + 16 + rA) * 32) + gsb,
                     As + BUFB + c0 * 1024 + 1024);
            gl2lds16((const unsigned char*)(Ebf + (size_t)(j0 + c0 * 16 + rA) * 32) + gsb,
                     Bs + BUFB + c0 * 1024);
            gl2lds16((const unsigned char*)(Ebf + (size_t)(j0 + c0 * 16 + 16 + rA) * 32) + gsb,
                     Bs + BUFB + c0 * 1024 + 1024);
        }                             // t == 12: nothing left to prefetch
        long2v aF[4], bF[4];
        #pragma unroll
        for (int mi = 0; mi < 4; ++mi)
            aF[mi] = *(const long2v*)&As[cur + (wy * 64 + mi * 16 + l15) * 64 + boX];
        #pragma unroll
        for (int ni = 0; ni < 4; ++ni)
            bF[ni] = *(const long2v*)&Bs[cur + (wx * 64 + ni * 16 + l15) * 64 + boX];
        #pragma unroll
        for (int mi = 0; mi < 4; ++mi)
            #pragma unroll
            for (int ni = 0; ni < 4; ++ni) {
                acc[mi][ni] = __builtin_amdgcn_mfma_f32_16x16x32_fp8_fp8(
                    aF[mi][0], bF[ni][0], acc[mi][ni], 0, 0, 0);
                acc[mi][ni] = __builtin_amdgcn_mfma_f32_16x16x32_fp8_fp8(
                    aF[mi][1], bF[ni][1], acc[mi][ni], 0, 0, 0);
            }
        cur = (cur == 2 * BUFB) ? 0 : cur + BUFB;
    }
    // E stage (buf 1): drain remaining DMA, sync all waves.
    asm volatile("s_waitcnt vmcnt(0)" ::: "memory");
    __builtin_amdgcn_s_barrier();

    // Epilogue. C/D layout: col = lane&15, row = quad*4 + reg  [m89/m91]
    // E-gram (bf16, buf 1; seg quad = cols 8q..8q+7, at swizzled pos quad^key)
    // streamed per mi to cap register pressure.
    const int slot_r = bj * 2 + wx;
    const int slot_c = bi * 2 + wy;
    bf16x8 bfrE[4];
    #pragma unroll
    for (int ni = 0; ni < 4; ++ni)
        bfrE[ni] = *(const bf16x8*)&Bs[BUFB + (wx * 64 + ni * 16 + l15) * 64 + boX];
    float cH[4] = {0,0,0,0}, cH2[4] = {0,0,0,0}, cL[4] = {0,0,0,0},
          cL2[4] = {0,0,0,0}, cHL[4] = {0,0,0,0};
    #pragma unroll
    for (int mi = 0; mi < 4; ++mi) {
        bf16x8 afE = *(const bf16x8*)&As[BUFB + (wy * 64 + mi * 16 + l15) * 64 + boX];
        f32x4 aE[4];
        #pragma unroll
        for (int ni = 0; ni < 4; ++ni) {
            f32x4 z = (f32x4){0.f, 0.f, 0.f, 0.f};
            aE[ni] = __builtin_amdgcn_mfma_f32_16x16x32_bf16(afE, bfrE[ni], z, 0, 0, 0);
        }
        const int ilocb = wy * 64 + mi * 16 + quad * 4;
        float sH[4] = {0,0,0,0}, sH2[4] = {0,0,0,0}, sL[4] = {0,0,0,0},
              sL2[4] = {0,0,0,0}, sHL[4] = {0,0,0,0};
        #pragma unroll
        for (int ni = 0; ni < 4; ++ni) {
            const int jloc = wx * 64 + ni * 16 + l15;
            const int j = j0 + jloc;
            const float sqxj = sqxs[128 + jloc];
            const float sqej = sqes[128 + jloc];
            #pragma unroll
            for (int r = 0; r < 4; ++r) {
                const int iloc = ilocb + r;
                const int i = i0 + iloc;
                float H, L;
                if (i == j) { H = 0.f; L = 0.f; }
                else {
                    float d2  = sqxs[iloc] + sqxj - 2.0f * acc[mi][ni][r];
                    H = sqrtf(fmaxf(d2, 0.f));
                    float d2e = sqes[iloc] + sqej - 2.0f * aE[ni][r];
                    L = sqrtf(fmaxf(d2e, 0.f));
                }
                sH[r] += H; sH2[r] += H * H; sL[r] += L; sL2[r] += L * L; sHL[r] += H * L;
                cH[ni] += H; cH2[ni] += H * H; cL[ni] += L; cL2[ni] += L * L; cHL[ni] += H * L;
            }
        }
        #pragma unroll
        for (int r = 0; r < 4; ++r) {
            float v0 = sH[r], v1 = sH2[r], v2 = sL[r], v3 = sL2[r], v4 = sHL[r];
            #pragma unroll
            for (int off2 = 1; off2 < 16; off2 <<= 1) {   // reduce over l15
                v0 += __shfl_xor(v0, off2, 64);
                v1 += __shfl_xor(v1, off2, 64);
                v2 += __shfl_xor(v2, off2, 64);
                v3 += __shfl_xor(v3, off2, 64);
                v4 += __shfl_xor(v4, off2, 64);
            }
            if (l15 == 0) {
                const int i = i0 + ilocb + r;
                float* base = statsp + (size_t)slot_r * NB + i;   // [c][slot][i]
                base[0 * SLAB] = v0;
                base[1 * SLAB] = v1;
                base[2 * SLAB] = v2;
                base[3 * SLAB] = v3;
                base[4 * SLAB] = v4;
            }
        }
    }
    if (bi != bj) {
        #pragma unroll
        for (int ni = 0; ni < 4; ++ni) {
            float v0 = cH[ni], v1 = cH2[ni], v2 = cL[ni], v3 = cL2[ni], v4 = cHL[ni];
            #pragma unroll
            for (int off2 = 16; off2 < 64; off2 <<= 1) {   // reduce over quad
                v0 += __shfl_xor(v0, off2, 64);
                v1 += __shfl_xor(v1, off2, 64);
                v2 += __shfl_xor(v2, off2, 64);
                v3 += __shfl_xor(v3, off2, 64);
                v4 += __shfl_xor(v4, off2, 64);
            }
            if (quad == 0) {
                const int j = j0 + wx * 64 + ni * 16 + l15;
                float* base = statsp + (size_t)slot_c * NB + j;
                base[0 * SLAB] = v0;
                base[1 * SLAB] = v1;
                base[2 * SLAB] = v2;
                base[3 * SLAB] = v3;
                base[4 * SLAB] = v4;
            }
        }
    }
}

// ---- finish1: reduce 64 slots per row, per-row corr; last block folds partials -> out
__global__ void finish1_kernel(const float* __restrict__ statsp, const float* __restrict__ upart,
                               float* __restrict__ cpart, unsigned* __restrict__ cnt,
                               float* __restrict__ out) {
    __shared__ float ps2[4][64][5];
    const int t = threadIdx.x;
    const int rloc = t & 63;
    const int sg = t >> 6;
    const int r = blockIdx.x * 64 + rloc;
    float sh = 0.f, sh2 = 0.f, sl = 0.f, sl2 = 0.f, shl = 0.f;
    for (int s = sg * 16; s < sg * 16 + 16; ++s) {
        const float* base = statsp + (size_t)s * NB + r;
        sh  += base[0 * SLAB];
        sh2 += base[1 * SLAB];
        sl  += base[2 * SLAB];
        sl2 += base[3 * SLAB];
        shl += base[4 * SLAB];
    }
    ps2[sg][rloc][0] = sh; ps2[sg][rloc][1] = sh2; ps2[sg][rloc][2] = sl;
    ps2[sg][rloc][3] = sl2; ps2[sg][rloc][4] = shl;
    __syncthreads();
    if (t < 64) {
        float a = 0.f, b = 0.f, c = 0.f, d = 0.f, e = 0.f;
        #pragma unroll
        for (int g = 0; g < 4; ++g) {
            a += ps2[g][t][0]; b += ps2[g][t][1]; c += ps2[g][t][2];
            d += ps2[g][t][3]; e += ps2[g][t][4];
        }
        const float invN = 1.0f / (float)NB;
        float num = e - a * c * invN;
        float vh  = fmaxf(b - a * a * invN, 0.f);
        float vl  = fmaxf(d - c * c * invN, 0.f);
        float local = num / (sqrtf(vh) * sqrtf(vl));
        #pragma unroll
        for (int off = 32; off; off >>= 1) local += __shfl_down(local, off, 64);
        if (t == 0) cpart[blockIdx.x] = local;
    }
    // last block folds 64 corr partials + 96 umap partials into the loss
    __shared__ int lastFlag;
    if (t == 0) {
        __threadfence();                       // cpart store visible device-wide
        unsigned prev = atomicAdd(cnt, 1u);
        lastFlag = (prev == 63u);
    }
    __syncthreads();
    if (lastFlag) {
        __threadfence();                       // acquire other blocks' cpart
        float v = 0.f;
        if (t < 64) v += cpart[t] * (-BETA_C / (float)NB);
        if (t < 96) v += upart[t] * (ALPHA_C / (float)NTOT);
        #pragma unroll
        for (int off = 32; off; off >>= 1) v += __shfl_down(v, off, 64);
        __shared__ float fin[4];
        if ((t & 63) == 0) fin[t >> 6] = v;
        __syncthreads();
        if (t == 0) out[0] = fin[0] + fin[1] + fin[2] + fin[3];
    }
}

extern "C" void kernel_launch(void* const* d_in, const int* in_sizes, int n_in,
                              void* d_out, int out_size, void* d_ws, size_t ws_size,
                              hipStream_t stream) {
    const float* emb  = (const float*)d_in[0];   // (4096, 32) f32
    const float* ph   = (const float*)d_in[1];   // (4096, 784) f32
    const int*   perm = (const int*)d_in[2];     // (20480,) i32
    float* out = (float*)d_out;

    char* ws = (char*)d_ws;
    unsigned char* Xf8 = (unsigned char*)(ws + WS_XF8);
    bf16*  Ebf    = (bf16*) (ws + WS_EBF);
    float* sqx    = (float*)(ws + WS_SQX);
    float* sqe    = (float*)(ws + WS_SQE);
    float* statsp = (float*)(ws + WS_STATSP);
    float* upart  = (float*)(ws + WS_UPART);
    float* cpart  = (float*)(ws + WS_CPART);
    unsigned* cnt = (unsigned*)(ws + WS_CNT);

    prep_fused<<<1120, 256, 0, stream>>>(ph, emb, perm, Xf8, sqx, Ebf, sqe, upart, cnt);
    gram_kernel<<<NBLK, 256, 0, stream>>>(Xf8, Ebf, sqx, sqe, statsp);
    finish1_kernel<<<64, 256, 0, stream>>>(statsp, upart, cpart, cnt, out);
}